// Round 1
// baseline (129.618 us; speedup 1.0000x reference)
//
#include <hip/hip_runtime.h>

// Sizes fixed by the problem
#define BW  512   // B*W = 8*64
#define NN  128   // N (nodes / output feature)
#define FF  128   // F
#define HH  4     // heads
#define HF  512   // H*F

// ---------------- Kernel 1: adjacency ----------------
// grid = 128 blocks (row i), block = 128 threads (col j)
// adj[i,j] = 1 if j is among top-k cosine sims of row i (jax.lax.top_k
// tie-break: equal values -> lower index wins)
__global__ void adj_kernel(const float* __restrict__ emb,
                           const int* __restrict__ kptr,
                           float* __restrict__ adj) {
    const int i = blockIdx.x;
    const int j = threadIdx.x;
    const int k = *kptr;

    __shared__ float s_ei[FF];    // normalized row i
    __shared__ float s_sim[NN];

    // load row i, compute its norm, normalize (matches ref: emb / ||emb||)
    float v = emb[i * FF + j];
    s_ei[j] = v;
    __syncthreads();
    float sq_i = 0.f;
    #pragma unroll 8
    for (int f = 0; f < FF; ++f) sq_i += s_ei[f] * s_ei[f];
    const float ni = sqrtf(sq_i);

    // row j norm
    float sq_j = 0.f;
    #pragma unroll 8
    for (int f = 0; f < FF; ++f) {
        float e = emb[j * FF + f];
        sq_j += e * e;
    }
    const float nj = sqrtf(sq_j);

    // dot of normalized rows (normalize-then-dot, like the reference)
    float dot = 0.f;
    #pragma unroll 8
    for (int f = 0; f < FF; ++f) {
        float a = s_ei[f] / ni;
        float b = emb[j * FF + f] / nj;
        dot = fmaf(a, b, dot);
    }
    s_sim[j] = dot;
    __syncthreads();

    // rank of element j: number of elements strictly better (ties -> lower idx)
    const float my = s_sim[j];
    int rank = 0;
    #pragma unroll 8
    for (int m = 0; m < NN; ++m) {
        float sm = s_sim[m];
        rank += (sm > my) | ((sm == my) & (m < j));
    }
    adj[i * NN + j] = (rank < k) ? 1.f : 0.f;
}

// ---------------- Kernel 2: h0 = X @ fp_W + fp_b ----------------
// grid = 512 (row r), block = 128 (col o)
__global__ void h0_kernel(const float* __restrict__ x,
                          const float* __restrict__ fpW,
                          const float* __restrict__ fpb,
                          float* __restrict__ h0) {
    const int r = blockIdx.x;
    const int o = threadIdx.x;
    __shared__ float sx[NN];
    sx[o] = x[r * NN + o];
    __syncthreads();
    float acc = fpb[o];
    #pragma unroll 8
    for (int n = 0; n < NN; ++n)
        acc = fmaf(sx[n], fpW[n * FF + o], acc);
    h0[r * FF + o] = acc;
}

// ---------------- Kernel 3: rg[r, h*F+o] = relu(sum_f h0[r,f]*gat_W[h,o,f]) --
// grid = 512 (row r), block = 512 (t = h*128+o)
__global__ void g_kernel(const float* __restrict__ h0,
                         const float* __restrict__ gatW,
                         float* __restrict__ rg) {
    const int r = blockIdx.x;
    const int t = threadIdx.x;   // t = h*FF + o; gatW[h][o][f] flat = t*FF + f
    __shared__ float sh[FF];
    if (t < FF) sh[t] = h0[r * FF + t];
    __syncthreads();
    const float* __restrict__ w = gatW + (size_t)t * FF;
    float acc = 0.f;
    #pragma unroll 8
    for (int f = 0; f < FF; ++f)
        acc = fmaf(sh[f], w[f], acc);
    rg[r * HF + t] = fmaxf(acc, 0.f);
}

// ---------------- Kernel 4: out = x*(1-m) + (rg @ op_W + op_b)*m ----------
// grid = 512 (row r), block = 128 (col j)
__global__ void out_kernel(const float* __restrict__ rg,
                           const float* __restrict__ opW,
                           const float* __restrict__ opb,
                           const float* __restrict__ x,
                           const float* __restrict__ mask,
                           float* __restrict__ out) {
    const int r = blockIdx.x;
    const int j = threadIdx.x;
    __shared__ float srg[HF];
    for (int c = j; c < HF; c += NN) srg[c] = rg[r * HF + c];
    __syncthreads();
    float acc = opb[j];
    #pragma unroll 8
    for (int c = 0; c < HF; ++c)
        acc = fmaf(srg[c], opW[c * NN + j], acc);
    const float xv = x[r * NN + j];
    const float m  = mask[r * NN + j];
    out[r * NN + j] = xv * (1.f - m) + acc * m;
}

extern "C" void kernel_launch(void* const* d_in, const int* in_sizes, int n_in,
                              void* d_out, int out_size, void* d_ws, size_t ws_size,
                              hipStream_t stream) {
    const float* x        = (const float*)d_in[0];  // (8,64,128)
    const float* mask     = (const float*)d_in[1];  // (8,64,128)
    const float* node_emb = (const float*)d_in[2];  // (128,128)
    const float* gat_W    = (const float*)d_in[3];  // (4,128,128)
    // d_in[4] = gat_a — provably unused (softmax over equal logits)
    const float* fp_W     = (const float*)d_in[5];  // (128,128)
    const float* fp_b     = (const float*)d_in[6];  // (128,)
    const float* op_W     = (const float*)d_in[7];  // (512,128)
    const float* op_b     = (const float*)d_in[8];  // (128,)
    const int*   kptr     = (const int*)d_in[9];    // scalar k=30

    float* out_main = (float*)d_out;               // 65536 floats
    float* out_adj  = (float*)d_out + BW * NN;     // 16384 floats

    float* h0 = (float*)d_ws;                      // 512*128
    float* rg = h0 + BW * FF;                      // 512*512

    adj_kernel<<<NN, NN, 0, stream>>>(node_emb, kptr, out_adj);
    h0_kernel <<<BW, NN, 0, stream>>>(x, fp_W, fp_b, h0);
    g_kernel  <<<BW, HF, 0, stream>>>(h0, gat_W, rg);
    out_kernel<<<BW, NN, 0, stream>>>(rg, op_W, op_b, x, mask, out_main);
}

// Round 2
// 121.718 us; speedup vs baseline: 1.0649x; 1.0649x over previous
//
#include <hip/hip_runtime.h>

// Sizes fixed by the problem
#define BW   512   // B*W = 8*64
#define NN   128   // N (nodes / output col)
#define FF   128   // F
#define HH   4     // heads
#define HF   512   // H*F
#define ROWS 4     // rows of X per main block
#define MAINB (BW / ROWS)   // 128 main blocks

// Single fused kernel.
// Blocks [0, MAINB)        : main path, ROWS rows each (h0 -> rg -> out)
// Blocks [MAINB, MAINB+NN) : adjacency rows
__global__ void __launch_bounds__(NN)
fused_kernel(const float* __restrict__ x,
             const float* __restrict__ mask,
             const float* __restrict__ emb,
             const float* __restrict__ gatW,
             const float* __restrict__ fpW,
             const float* __restrict__ fpb,
             const float* __restrict__ opW,
             const float* __restrict__ opb,
             const int*   __restrict__ kptr,
             float* __restrict__ out_main,
             float* __restrict__ out_adj) {
    const int b = blockIdx.x;
    const int o = threadIdx.x;   // 0..127

    if (b < MAINB) {
        // ---------------- main path: rows r0..r0+3 ----------------
        const int r0 = b * ROWS;
        __shared__ float sx [ROWS][FF];
        __shared__ float sh [ROWS][FF];
        __shared__ float srg[ROWS][HF];

        #pragma unroll
        for (int rr = 0; rr < ROWS; ++rr)
            sx[rr][o] = x[(r0 + rr) * NN + o];
        __syncthreads();

        // Stage 1: h0 = x @ fpW + fpb   (coalesced fpW reads)
        {
            const float bias = fpb[o];
            float a0 = bias, a1 = bias, a2 = bias, a3 = bias;
            #pragma unroll 4
            for (int n = 0; n < NN; ++n) {
                const float w = fpW[n * FF + o];
                a0 = fmaf(sx[0][n], w, a0);
                a1 = fmaf(sx[1][n], w, a1);
                a2 = fmaf(sx[2][n], w, a2);
                a3 = fmaf(sx[3][n], w, a3);
            }
            sh[0][o] = a0; sh[1][o] = a1; sh[2][o] = a2; sh[3][o] = a3;
        }
        __syncthreads();

        // Stage 2: rg[rr][h*F+o] = relu(sum_f sh[rr][f] * gatW[h][o][f])
        // gatW per-lane contiguous along f -> float4 loads
        {
            float acc[ROWS][HH];
            #pragma unroll
            for (int rr = 0; rr < ROWS; ++rr)
                #pragma unroll
                for (int h = 0; h < HH; ++h) acc[rr][h] = 0.f;

            const float4* __restrict__ gw = (const float4*)gatW;
            const int base = o * FF / 4;          // float4 index of gatW[0][o][0]
            #pragma unroll 2
            for (int f4 = 0; f4 < FF / 4; ++f4) {
                float4 w[HH];
                #pragma unroll
                for (int h = 0; h < HH; ++h)
                    w[h] = gw[h * (FF * FF / 4) + base + f4];
                #pragma unroll
                for (int rr = 0; rr < ROWS; ++rr) {
                    const float s0 = sh[rr][f4 * 4 + 0];
                    const float s1 = sh[rr][f4 * 4 + 1];
                    const float s2 = sh[rr][f4 * 4 + 2];
                    const float s3 = sh[rr][f4 * 4 + 3];
                    #pragma unroll
                    for (int h = 0; h < HH; ++h) {
                        acc[rr][h] = fmaf(s0, w[h].x, acc[rr][h]);
                        acc[rr][h] = fmaf(s1, w[h].y, acc[rr][h]);
                        acc[rr][h] = fmaf(s2, w[h].z, acc[rr][h]);
                        acc[rr][h] = fmaf(s3, w[h].w, acc[rr][h]);
                    }
                }
            }
            #pragma unroll
            for (int rr = 0; rr < ROWS; ++rr)
                #pragma unroll
                for (int h = 0; h < HH; ++h)
                    srg[rr][h * FF + o] = fmaxf(acc[rr][h], 0.f);
        }
        __syncthreads();

        // Stage 3: out = x*(1-m) + (rg @ opW + opb)*m   (coalesced opW reads)
        {
            const float bias = opb[o];
            float c0 = bias, c1 = bias, c2 = bias, c3 = bias;
            #pragma unroll 4
            for (int c = 0; c < HF; ++c) {
                const float w = opW[c * NN + o];
                c0 = fmaf(srg[0][c], w, c0);
                c1 = fmaf(srg[1][c], w, c1);
                c2 = fmaf(srg[2][c], w, c2);
                c3 = fmaf(srg[3][c], w, c3);
            }
            float acc[ROWS] = {c0, c1, c2, c3};
            #pragma unroll
            for (int rr = 0; rr < ROWS; ++rr) {
                const int idx = (r0 + rr) * NN + o;
                const float m = mask[idx];
                out_main[idx] = x[idx] * (1.f - m) + acc[rr] * m;
            }
        }
    } else {
        // ---------------- adjacency row i ----------------
        const int i = b - MAINB;
        const int j = o;
        const int k = *kptr;

        __shared__ float s_ei[FF];
        __shared__ float s_sim[NN];

        s_ei[j] = emb[i * FF + j];
        __syncthreads();
        float sq_i = 0.f;
        #pragma unroll 8
        for (int f = 0; f < FF; ++f) sq_i += s_ei[f] * s_ei[f];
        const float ni = sqrtf(sq_i);

        float sq_j = 0.f;
        const float4* ej4 = (const float4*)(emb + j * FF);
        float4 ej[FF / 4 / 8];  // not enough regs for all; stream twice instead
        (void)ej;
        #pragma unroll 8
        for (int f = 0; f < FF; ++f) {
            const float e = emb[j * FF + f];
            sq_j += e * e;
        }
        const float nj = sqrtf(sq_j);

        // dot of normalized rows (normalize-then-dot, matches reference rounding)
        float dot = 0.f;
        #pragma unroll 8
        for (int f = 0; f < FF; ++f) {
            const float a = s_ei[f] / ni;
            const float bb = emb[j * FF + f] / nj;
            dot = fmaf(a, bb, dot);
        }
        s_sim[j] = dot;
        __syncthreads();

        // rank with jax.lax.top_k tie-break (equal value -> lower index wins)
        const float my = s_sim[j];
        int rank = 0;
        #pragma unroll 8
        for (int m = 0; m < NN; ++m) {
            const float sm = s_sim[m];
            rank += (sm > my) | ((sm == my) & (m < j));
        }
        out_adj[i * NN + j] = (rank < k) ? 1.f : 0.f;
    }
}

extern "C" void kernel_launch(void* const* d_in, const int* in_sizes, int n_in,
                              void* d_out, int out_size, void* d_ws, size_t ws_size,
                              hipStream_t stream) {
    const float* x        = (const float*)d_in[0];  // (8,64,128)
    const float* mask     = (const float*)d_in[1];  // (8,64,128)
    const float* node_emb = (const float*)d_in[2];  // (128,128)
    const float* gat_W    = (const float*)d_in[3];  // (4,128,128)
    // d_in[4] = gat_a — provably unused (softmax over identical logits)
    const float* fp_W     = (const float*)d_in[5];  // (128,128)
    const float* fp_b     = (const float*)d_in[6];  // (128,)
    const float* op_W     = (const float*)d_in[7];  // (512,128)
    const float* op_b     = (const float*)d_in[8];  // (128,)
    const int*   kptr     = (const int*)d_in[9];    // scalar k=30

    float* out_main = (float*)d_out;               // 65536 floats
    float* out_adj  = (float*)d_out + BW * NN;     // 16384 floats

    fused_kernel<<<MAINB + NN, NN, 0, stream>>>(
        x, mask, node_emb, gat_W, fp_W, fp_b, op_W, op_b, kptr,
        out_main, out_adj);
}

// Round 3
// 85.439 us; speedup vs baseline: 1.5171x; 1.4246x over previous
//
#include <hip/hip_runtime.h>

// Problem sizes (fixed)
#define BW   512        // B*W
#define NN   128        // nodes / output cols
#define FF   128        // F
#define HH   4          // heads
#define HF   512        // H*F
#define ROWS 4          // x-rows per main block
#define MAINB (BW / ROWS)        // 128 main blocks
#define ADJR 4                   // adjacency rows per block
#define ADJB (NN / ADJR)         // 32 adjacency blocks
#define NT   512        // threads per block

// One launch, 160 blocks, one block per CU.
// Blocks [0,128): main path (4 rows each).  Blocks [128,160): adjacency (4 rows each).
__global__ void __launch_bounds__(NT)
fused_kernel(const float* __restrict__ x,
             const float* __restrict__ mask,
             const float* __restrict__ emb,
             const float* __restrict__ gatW,
             const float* __restrict__ fpW,
             const float* __restrict__ fpb,
             const float* __restrict__ opW,
             const float* __restrict__ opb,
             const int*   __restrict__ kptr,
             float* __restrict__ out_main,
             float* __restrict__ out_adj) {
    const int b = blockIdx.x;
    const int u = threadIdx.x;          // 0..511

    // ---- main-path LDS (20 KB) ----
    __shared__ float sx  [ROWS][NN];    // x rows
    __shared__ float sh  [ROWS][FF];    // h0 rows
    __shared__ float srg [ROWS][HF];    // relu(g) rows
    __shared__ float psum[4][ROWS][NN]; // partial sums (stage1 & stage3)
    // ---- adjacency LDS (~69 KB) ----
    __shared__ float s_emb[NN][FF + 1]; // padded: (j+f)%32 banks -> 2-way = free
    __shared__ float s_np [NN][4];      // norm partials
    __shared__ float s_nrm[NN];
    __shared__ float s_sim[ADJR][NN];

    if (b < MAINB) {
        // =============== MAIN PATH: rows r0..r0+3 ===============
        const int r0 = b * ROWS;
        // load 4 x-rows, coalesced:  sx flat[t] = x[r0*NN + t]
        sx[u >> 7][u & 127] = x[r0 * NN + u];
        __syncthreads();

        // ---- Stage 1: h0 = x @ fpW + fpb  (n split 4 ways, 32-iter loops)
        {
            const int ng = u >> 7;       // n-quarter
            const int o  = u & 127;      // output col
            float a0 = 0.f, a1 = 0.f, a2 = 0.f, a3 = 0.f;
            const int n0 = ng * 32;
            #pragma unroll 8
            for (int nn = 0; nn < 32; ++nn) {
                const int n = n0 + nn;
                const float w = fpW[n * FF + o];       // coalesced
                a0 = fmaf(sx[0][n], w, a0);
                a1 = fmaf(sx[1][n], w, a1);
                a2 = fmaf(sx[2][n], w, a2);
                a3 = fmaf(sx[3][n], w, a3);
            }
            psum[ng][0][o] = a0; psum[ng][1][o] = a1;
            psum[ng][2][o] = a2; psum[ng][3][o] = a3;
        }
        __syncthreads();
        {   // reduce: thread u -> (rr, o)
            const int rr = u >> 7, o = u & 127;
            sh[rr][o] = fpb[o] + psum[0][rr][o] + psum[1][rr][o]
                                + psum[2][rr][o] + psum[3][rr][o];
        }
        __syncthreads();

        // ---- Stage 2: rg[rr][t] = relu(sum_f sh[rr][f]*gatW[t][f])  (t=h*F+o)
        {
            float acc0 = 0.f, acc1 = 0.f, acc2 = 0.f, acc3 = 0.f;
            const float4* __restrict__ gw = (const float4*)(gatW + (size_t)u * FF);
            #pragma unroll 4
            for (int f4 = 0; f4 < FF / 4; ++f4) {
                const float4 w = gw[f4];               // per-lane contiguous 16B
                const int f = f4 * 4;
                acc0 = fmaf(sh[0][f], w.x, fmaf(sh[0][f+1], w.y, fmaf(sh[0][f+2], w.z, fmaf(sh[0][f+3], w.w, acc0))));
                acc1 = fmaf(sh[1][f], w.x, fmaf(sh[1][f+1], w.y, fmaf(sh[1][f+2], w.z, fmaf(sh[1][f+3], w.w, acc1))));
                acc2 = fmaf(sh[2][f], w.x, fmaf(sh[2][f+1], w.y, fmaf(sh[2][f+2], w.z, fmaf(sh[2][f+3], w.w, acc2))));
                acc3 = fmaf(sh[3][f], w.x, fmaf(sh[3][f+1], w.y, fmaf(sh[3][f+2], w.z, fmaf(sh[3][f+3], w.w, acc3))));
            }
            srg[0][u] = fmaxf(acc0, 0.f);
            srg[1][u] = fmaxf(acc1, 0.f);
            srg[2][u] = fmaxf(acc2, 0.f);
            srg[3][u] = fmaxf(acc3, 0.f);
        }
        __syncthreads();

        // ---- Stage 3: imputed = rg @ opW + opb  (c split 4 ways, 128-iter loops)
        {
            const int cg = u >> 7;       // c-quarter (wave-uniform)
            const int j  = u & 127;
            float a0 = 0.f, a1 = 0.f, a2 = 0.f, a3 = 0.f;
            const int t0 = cg * 128;
            #pragma unroll 8
            for (int tt = 0; tt < 128; ++tt) {
                const int t = t0 + tt;
                const float w = opW[t * NN + j];       // coalesced
                a0 = fmaf(srg[0][t], w, a0);           // broadcast LDS reads
                a1 = fmaf(srg[1][t], w, a1);
                a2 = fmaf(srg[2][t], w, a2);
                a3 = fmaf(srg[3][t], w, a3);
            }
            psum[cg][0][j] = a0; psum[cg][1][j] = a1;
            psum[cg][2][j] = a2; psum[cg][3][j] = a3;
        }
        __syncthreads();
        {   // epilogue: thread u -> (rr, j)
            const int rr = u >> 7, j = u & 127;
            const float val = opb[j] + psum[0][rr][j] + psum[1][rr][j]
                                      + psum[2][rr][j] + psum[3][rr][j];
            const int idx = (r0 + rr) * NN + j;
            const float m = mask[idx];
            out_main[idx] = x[idx] * (1.f - m) + val * m;
        }
    } else {
        // =============== ADJACENCY: rows i0..i0+3 ===============
        const int i0 = (b - MAINB) * ADJR;
        const int k  = *kptr;

        // 1) load all of emb into LDS, coalesced float4 from global
        {
            const float4* __restrict__ e4 = (const float4*)emb;
            #pragma unroll
            for (int it = 0; it < (NN * FF / 4) / NT; ++it) {   // 8 iters
                const int e = it * NT + u;        // float4 index
                const float4 v = e4[e];
                const int row = e >> 5;           // e / 32
                const int c4  = (e & 31) * 4;
                s_emb[row][c4 + 0] = v.x;
                s_emb[row][c4 + 1] = v.y;
                s_emb[row][c4 + 2] = v.z;
                s_emb[row][c4 + 3] = v.w;
            }
        }
        __syncthreads();

        // 2) row norms: 4 partials per row
        {
            const int row = u >> 2, part = u & 3;
            float s = 0.f;
            const int f0 = part * 32;
            #pragma unroll 8
            for (int f = 0; f < 32; ++f) {
                const float e = s_emb[row][f0 + f];
                s = fmaf(e, e, s);
            }
            s_np[row][part] = s;
        }
        __syncthreads();
        if (u < NN)
            s_nrm[u] = sqrtf(s_np[u][0] + s_np[u][1] + s_np[u][2] + s_np[u][3]);
        __syncthreads();
        // 3) normalize in place (matches reference: emb / ||emb||, then dot)
        #pragma unroll
        for (int it = 0; it < (NN * FF) / NT; ++it) {           // 32 iters
            const int e = it * NT + u;
            const int row = e >> 7, col = e & 127;
            s_emb[row][col] /= s_nrm[row];
        }
        __syncthreads();

        // 4) sim[g][j] = dot(emb_n[i0+g], emb_n[j])
        {
            const int g = u >> 7;        // wave-uniform
            const int j = u & 127;
            const int i = i0 + g;
            float d = 0.f;
            #pragma unroll 8
            for (int f = 0; f < FF; ++f)
                d = fmaf(s_emb[i][f], s_emb[j][f], d);  // broadcast * 2-way
            s_sim[g][j] = d;
        }
        __syncthreads();

        // 5) rank (jax.lax.top_k tie-break: equal value -> lower index wins)
        {
            const int g = u >> 7;
            const int j = u & 127;
            const float my = s_sim[g][j];
            int rank = 0;
            #pragma unroll 8
            for (int m = 0; m < NN; ++m) {
                const float sm = s_sim[g][m];           // broadcast
                rank += (sm > my) | ((sm == my) & (m < j));
            }
            out_adj[(i0 + g) * NN + j] = (rank < k) ? 1.f : 0.f;
        }
    }
}

extern "C" void kernel_launch(void* const* d_in, const int* in_sizes, int n_in,
                              void* d_out, int out_size, void* d_ws, size_t ws_size,
                              hipStream_t stream) {
    const float* x        = (const float*)d_in[0];  // (8,64,128)
    const float* mask     = (const float*)d_in[1];  // (8,64,128)
    const float* node_emb = (const float*)d_in[2];  // (128,128)
    const float* gat_W    = (const float*)d_in[3];  // (4,128,128)
    // d_in[4] = gat_a — provably unused (softmax over identical logits)
    const float* fp_W     = (const float*)d_in[5];  // (128,128)
    const float* fp_b     = (const float*)d_in[6];  // (128,)
    const float* op_W     = (const float*)d_in[7];  // (512,128)
    const float* op_b     = (const float*)d_in[8];  // (128,)
    const int*   kptr     = (const int*)d_in[9];    // scalar k=30

    float* out_main = (float*)d_out;               // 65536 floats
    float* out_adj  = (float*)d_out + BW * NN;     // 16384 floats

    fused_kernel<<<MAINB + ADJB, NT, 0, stream>>>(
        x, mask, node_emb, gat_W, fp_W, fp_b, op_W, op_b, kptr,
        out_main, out_adj);
}